// Round 7
// baseline (468.257 us; speedup 1.0000x reference)
//
#include <hip/hip_runtime.h>

#define N_TOT 211072   // B*V = 32*6596
#define V_MESH 6596
#define E_TOT 633216   // 3*N
#define CAP 32
#define KP 184         // feats row width in bf16 (368B; MFMA reads cols 0..159)
#define KSTEPS 5       // 5*32 = 160 >= 131
#define MM3_BPM 207    // mm3 blocks/mesh (32 rows): 207*32 >= 6596
#define FUS_BPM 413    // fused blocks/mesh (16 rows): 413*16 >= 6596
#define FIN_BPM 1649   // final blocks/mesh (4 rows): exact 1649*4 = 6596

typedef __attribute__((ext_vector_type(8))) short bf16x8;
typedef __attribute__((ext_vector_type(4))) float f32x4;

__constant__ float c_LIM[14] = {0.04f,0.06f,0.04f,0.04f,0.02f,0.02f,0.04f,0.04f,
                                0.03f,0.03f,0.02f,0.02f,0.01f,0.01f};

__device__ __forceinline__ unsigned f2bf(float f) {   // RNE f32->bf16
    unsigned x = __float_as_uint(f);
    return (x + 0x7fffu + ((x >> 16) & 1u)) >> 16;
}
__device__ __forceinline__ float bflo(unsigned u) { return __uint_as_float(u << 16); }
__device__ __forceinline__ float bfhi(unsigned u) { return __uint_as_float(u & 0xffff0000u); }
// truncating pack: low16 = hi16(a0), high16 = hi16(a1)  (one v_perm_b32)
__device__ __forceinline__ unsigned pk_trunc(float a0, float a1) {
    return __builtin_amdgcn_perm(__float_as_uint(a1), __float_as_uint(a0), 0x07060302u);
}

// ---------------- adjacency build ----------------
__global__ __launch_bounds__(256) void fill_adj_kernel(const int* __restrict__ edges,
                                                       int* __restrict__ cnt,
                                                       int* __restrict__ adj) {
    int e = blockIdx.x * 256 + threadIdx.x;
    if (e >= E_TOT) return;
    int2 ed = ((const int2*)edges)[e];
    int p0 = atomicAdd(&cnt[ed.x], 1);
    if (p0 < CAP) adj[(size_t)ed.x * CAP + p0] = ed.y;
    int p1 = atomicAdd(&cnt[ed.y], 1);
    if (p1 < CAP) adj[(size_t)ed.y * CAP + p1] = ed.x;
}

// ---------------- pad adjacency rows with sentinel up to 8-multiple ----------------
__global__ __launch_bounds__(256) void pad_adj_kernel(const int* __restrict__ cnt,
                                                      int* __restrict__ adj) {
    int i = blockIdx.x * 256 + threadIdx.x;
    if (i >= N_TOT) return;
    int deg = cnt[i]; if (deg > CAP) deg = CAP;
    int end = (deg <= 8) ? 8 : ((deg + 7) & ~7);
    if (end > CAP) end = CAP;
    for (int k = deg; k < end; ++k) adj[(size_t)i * CAP + k] = N_TOT;
}

// ---------------- weight conversion: Wt[256][184] bf16 (transposed, zero-padded), bb[256] ----------------
__global__ __launch_bounds__(256) void conv_w_kernel(const float* __restrict__ w0,
                                                     const float* __restrict__ b0,
                                                     const float* __restrict__ w1,
                                                     const float* __restrict__ b1,
                                                     short* __restrict__ Wt,
                                                     float* __restrict__ bb) {
    int c = blockIdx.x;          // 0..255 output col
    int k = threadIdx.x;         // 0..255
    const float* w = (c < 128) ? w0 : w1;
    int cc = c & 127;
    if (k < KP) {
        unsigned val = (k < 131) ? f2bf(w[(size_t)k * 128 + cc]) : 0u;
        Wt[(size_t)c * KP + k] = (short)val;
    }
    if (k == 0) bb[c] = (c < 128) ? b0[cc] : b1[cc];
}

// ---------------- layer 0 matmul (feats = normals, d=3) -> xc interleaved bf16 ----------------
// XCD swizzle: mesh m handled by blocks with blockIdx%8 == m%8 (same as consumers).
__global__ __launch_bounds__(256) void mm3_kernel(const float* __restrict__ normals,
                                                  const float* __restrict__ w0,
                                                  const float* __restrict__ b0,
                                                  const float* __restrict__ w1,
                                                  const float* __restrict__ b1,
                                                  unsigned* __restrict__ xc) { // [N+1][128] dwords
    __shared__ float nL[32][3];
    int t = threadIdx.x;
    int d = blockIdx.x, tt = d >> 3;
    int m  = (d & 7) + 8 * (tt / MM3_BPM);
    int r0 = (tt % MM3_BPM) * 32;           // row within mesh
    int base = m * V_MESH;
    if (t < 96) {
        int r = t / 3, k = t - r * 3;
        int rr = r0 + r; if (rr >= V_MESH) rr = V_MESH - 1;
        nL[r][k] = normals[(size_t)(base + rr) * 3 + k];
    }
    __syncthreads();
    int mm = (t >> 6) & 1;   // 0 -> x0 half, 1 -> x1 half
    int rh = t >> 7;
    int c2 = t & 63;         // column pair 2*c2, 2*c2+1
    const float* w = mm ? w1 : w0;
    const float* b = mm ? b1 : b0;
    float wA0 = w[0*128 + 2*c2],     wA1 = w[1*128 + 2*c2],     wA2 = w[2*128 + 2*c2];
    float wB0 = w[0*128 + 2*c2 + 1], wB1 = w[1*128 + 2*c2 + 1], wB2 = w[2*128 + 2*c2 + 1];
    float bA = b[2*c2], bB = b[2*c2 + 1];
    #pragma unroll
    for (int r = 0; r < 16; ++r) {
        int lr = rh * 16 + r;
        if (r0 + lr < V_MESH) {
            float vA = bA + nL[lr][0]*wA0 + nL[lr][1]*wA1 + nL[lr][2]*wA2;
            float vB = bB + nL[lr][0]*wB0 + nL[lr][1]*wB1 + nL[lr][2]*wB2;
            xc[(size_t)(base + r0 + lr) * 128 + mm * 64 + c2] = f2bf(vA) | (f2bf(vB) << 16);
        }
    }
}

// ---------------- fused: 8-deep branch-free gather + relu -> LDS tile -> MFMA -> xc' ----------------
// 1024 threads = 16 waves; wave w owns one node. Lane l owns cols (2l, 2l+1).
// XCD swizzle keeps each mesh's gather working set in one XCD's L2.
__global__ __launch_bounds__(1024, 8) void fused_kernel(const unsigned* __restrict__ xc_in, // [N+1][128]
                                                        const float* __restrict__ normals,
                                                        const int* __restrict__ cnt,
                                                        const int* __restrict__ adj,
                                                        const short* __restrict__ Wt,      // [256][184]
                                                        const float* __restrict__ bb,      // [256]
                                                        unsigned* __restrict__ xc_out) {   // [N+1][128]
    __shared__ short tileA[16 * KP];     // 5888 B gathered feats
    __shared__ short tileC[16 * 256];    // 8192 B output staging (pair-packed, swizzled)
    int tid  = threadIdx.x;
    int w    = tid >> 6;
    int lane = tid & 63;
    int g    = lane >> 4;
    int ln   = lane & 15;

    int d  = blockIdx.x, tt = d >> 3;
    int m  = (d & 7) + 8 * (tt / FUS_BPM);
    int r16 = (tt % FUS_BPM) * 16;
    int base = m * V_MESH;
    bool valid = (r16 + w) < V_MESH;
    int i = base + (valid ? r16 + w : V_MESH - 1);

    // ---- early independent loads ----
    int deg0 = cnt[i];
    int jv = (lane < CAP) ? adj[(size_t)i * CAP + lane] : (int)N_TOT;
    unsigned selfu = xc_in[(size_t)i * 128 + lane];          // x0 dword (cols 2l,2l+1)
    float nv = (lane < 3) ? normals[(size_t)i * 3 + lane] : 0.f;
    int cb = w * 16;
    float bv = bb[cb + ln];
    bf16x8 bfrag[KSTEPS];
    #pragma unroll
    for (int kk = 0; kk < KSTEPS; ++kk)
        bfrag[kk] = *(const bf16x8*)(Wt + (size_t)(cb + ln) * KP + kk * 32 + g * 8);

    // ---- round 0: 8 unconditional gathers, all in flight ----
    const unsigned* x1b = xc_in + 64 + lane;   // + jj*128
    unsigned u[8];
    #pragma unroll
    for (int q = 0; q < 8; ++q) {
        int j = __builtin_amdgcn_readlane(jv, q);
        u[q] = x1b[(size_t)j * 128];
    }
    float a0 = bflo(selfu), a1 = bfhi(selfu);
    float d0 = 0.f, d1 = 0.f;
    #pragma unroll
    for (int q = 0; q < 8; q += 2) {
        a0 += bflo(u[q]);     a1 += bfhi(u[q]);
        d0 += bflo(u[q + 1]); d1 += bfhi(u[q + 1]);
    }
    // ---- extra rounds (deg > 8, uncommon) ----
    int deg = (deg0 > CAP) ? CAP : deg0;
    deg = __builtin_amdgcn_readfirstlane(deg);
    for (int bq = 8; bq < deg; bq += 8) {
        unsigned v[8];
        #pragma unroll
        for (int q = 0; q < 8; ++q) {
            int j = __builtin_amdgcn_readlane(jv, bq + q);
            v[q] = x1b[(size_t)j * 128];
        }
        #pragma unroll
        for (int q = 0; q < 8; q += 2) {
            a0 += bflo(v[q]);     a1 += bfhi(v[q]);
            d0 += bflo(v[q + 1]); d1 += bfhi(v[q + 1]);
        }
    }
    a0 = fmaxf(a0 + d0, 0.f);
    a1 = fmaxf(a1 + d1, 0.f);

    // ---- write tile row: dwords 0..63 = h (perm trunc pack), 64..79 = normals + pad ----
    ((unsigned*)tileA)[w * (KP / 2) + lane] = pk_trunc(a0, a1);
    unsigned nb = f2bf(nv);
    unsigned nb0 = __shfl((int)nb, 0), nb1 = __shfl((int)nb, 1), nb2 = __shfl((int)nb, 2);
    if (lane < 16) {
        unsigned v = (lane == 0) ? (nb0 | (nb1 << 16)) : (lane == 1) ? nb2 : 0u;
        ((unsigned*)tileA)[w * (KP / 2) + 64 + lane] = v;
    }
    __syncthreads();

    // ---- MFMA: wave w computes 16 rows x 16 cols (col block w*16) over K=160 ----
    f32x4 acc = {bv, bv, bv, bv};
    #pragma unroll
    for (int kk = 0; kk < KSTEPS; ++kk) {
        bf16x8 af = *(const bf16x8*)(tileA + ln * KP + kk * 32 + g * 8);
        acc = __builtin_amdgcn_mfma_f32_16x16x32_bf16(af, bfrag[kk], acc, 0, 0, 0);
    }
    // pair-pack cols via shfl, dword stores, XOR-swizzle by lane-group -> conflict-free
    #pragma unroll
    for (int j = 0; j < 4; ++j) {
        float po = __shfl_xor(acc[j], 1);
        if (!(ln & 1)) {
            unsigned pk = f2bf(acc[j]) | (f2bf(po) << 16);
            int dd = w * 8 + (ln >> 1);          // true dword within row
            int row = g * 4 + j;
            ((unsigned*)tileC)[row * 128 + (dd ^ (g << 3))] = pk;
        }
    }
    __syncthreads();

    // ---- coalesced row writeback (inverse swizzle; key = row's writer-group) ----
    if (valid) {
        int key = (w >> 2) << 3;
        ushort4 v4 = *(const ushort4*)&((unsigned*)tileC)[w * 128 + ((2 * lane) ^ key)];
        ((ushort4*)(xc_out + (size_t)i * 128))[lane] = v4;
    }
}

// ---------------- final: 8-deep gather + relu -> h (f32) + deform + vertex update ----------------
__global__ __launch_bounds__(256) void final_fused_kernel(const unsigned* __restrict__ xc_in,
                                                          const int* __restrict__ cnt,
                                                          const int* __restrict__ adj,
                                                          const float* __restrict__ normals,
                                                          const float* __restrict__ verts,
                                                          const float* __restrict__ anchor_v,
                                                          const int* __restrict__ part_id,
                                                          const float* __restrict__ w_off,
                                                          const float* __restrict__ b_off,
                                                          float* __restrict__ hout,
                                                          float* __restrict__ out_verts) {
    __shared__ float wo[131 * 3];
    for (int t = threadIdx.x; t < 131 * 3; t += 256) wo[t] = w_off[t];
    __syncthreads();
    int tid  = threadIdx.x;
    int w    = tid >> 6;
    int lane = tid & 63;
    int d  = blockIdx.x, tt = d >> 3;
    int m  = (d & 7) + 8 * (tt / FIN_BPM);
    int i  = m * V_MESH + (tt % FIN_BPM) * 4 + w;   // exact decomposition

    int deg0 = cnt[i];
    int jv = (lane < CAP) ? adj[(size_t)i * CAP + lane] : (int)N_TOT;
    unsigned selfu = xc_in[(size_t)i * 128 + lane];

    const unsigned* x1b = xc_in + 64 + lane;
    unsigned u[8];
    #pragma unroll
    for (int q = 0; q < 8; ++q) {
        int j = __builtin_amdgcn_readlane(jv, q);
        u[q] = x1b[(size_t)j * 128];
    }
    float a0 = bflo(selfu), a1 = bfhi(selfu);
    float d0 = 0.f, d1 = 0.f;
    #pragma unroll
    for (int q = 0; q < 8; q += 2) {
        a0 += bflo(u[q]);     a1 += bfhi(u[q]);
        d0 += bflo(u[q + 1]); d1 += bfhi(u[q + 1]);
    }
    int deg = (deg0 > CAP) ? CAP : deg0;
    deg = __builtin_amdgcn_readfirstlane(deg);
    for (int bq = 8; bq < deg; bq += 8) {
        unsigned v[8];
        #pragma unroll
        for (int q = 0; q < 8; ++q) {
            int j = __builtin_amdgcn_readlane(jv, bq + q);
            v[q] = x1b[(size_t)j * 128];
        }
        #pragma unroll
        for (int q = 0; q < 8; q += 2) {
            a0 += bflo(v[q]);     a1 += bfhi(v[q]);
            d0 += bflo(v[q + 1]); d1 += bfhi(v[q + 1]);
        }
    }
    a0 = fmaxf(a0 + d0, 0.f);
    a1 = fmaxf(a1 + d1, 0.f);

    // h store: lane l writes cols (2l, 2l+1) -> full 512B row per wave
    float2 hv; hv.x = a0; hv.y = a1;
    ((float2*)(hout + (size_t)i * 128))[lane] = hv;

    // offset head: partial dot over this lane's 2 cols, full-wave reduce
    int cA = 2 * lane, cB = 2 * lane + 1;
    float s0 = a0 * wo[cA * 3 + 0] + a1 * wo[cB * 3 + 0];
    float s1 = a0 * wo[cA * 3 + 1] + a1 * wo[cB * 3 + 1];
    float s2 = a0 * wo[cA * 3 + 2] + a1 * wo[cB * 3 + 2];
    #pragma unroll
    for (int dd = 32; dd; dd >>= 1) {
        s0 += __shfl_xor(s0, dd);
        s1 += __shfl_xor(s1, dd);
        s2 += __shfl_xor(s2, dd);
    }
    if (lane < 3) {
        int v = i % V_MESH;
        float n0 = normals[(size_t)i * 3 + 0];
        float n1 = normals[(size_t)i * 3 + 1];
        float n2 = normals[(size_t)i * 3 + 2];
        float s = (lane == 0) ? s0 : (lane == 1) ? s1 : s2;
        s += n0 * wo[128 * 3 + lane] + n1 * wo[129 * 3 + lane] + n2 * wo[130 * 3 + lane];
        s += b_off[lane];
        float dd2 = tanhf(s);
        float lim = c_LIM[part_id[v]];
        dd2 = fminf(fmaxf(dd2, -lim), lim);
        out_verts[(size_t)i * 3 + lane] =
            verts[(size_t)i * 3 + lane] + dd2 * anchor_v[(size_t)v * 3 + lane];
    }
}

extern "C" void kernel_launch(void* const* d_in, const int* in_sizes, int n_in,
                              void* d_out, int out_size, void* d_ws, size_t ws_size,
                              hipStream_t stream) {
    const float* verts    = (const float*)d_in[0];
    const float* normals  = (const float*)d_in[1];
    const float* anchor_v = (const float*)d_in[2];
    const int*   edges    = (const int*)d_in[3];
    const int*   part_id  = (const int*)d_in[4];
    const float* w0_0 = (const float*)d_in[5];
    const float* b0_0 = (const float*)d_in[6];
    const float* w1_0 = (const float*)d_in[7];
    const float* b1_0 = (const float*)d_in[8];
    const float* w0_1 = (const float*)d_in[9];
    const float* b0_1 = (const float*)d_in[10];
    const float* w1_1 = (const float*)d_in[11];
    const float* b1_1 = (const float*)d_in[12];
    const float* w0_2 = (const float*)d_in[13];
    const float* b0_2 = (const float*)d_in[14];
    const float* w1_2 = (const float*)d_in[15];
    const float* b1_2 = (const float*)d_in[16];
    const float* w_off = (const float*)d_in[17];
    const float* b_off = (const float*)d_in[18];

    float* out_verts = (float*)d_out;
    float* hout = (float*)d_out + (size_t)3 * N_TOT;   // final h (f32)

    // pair B aliases ALL of d_out (verts+h regions dead until final): [N+1][128] dwords
    unsigned* xcB = (unsigned*)d_out;

    char* p = (char*)d_ws;
    unsigned* xcA = (unsigned*)p;  p += (size_t)(N_TOT + 1) * 128 * 4;
    int*   cnt = (int*)p;          p += (size_t)N_TOT * 4;
    int*   adj = (int*)p;          p += (size_t)N_TOT * CAP * 4;
    short* Wt1 = (short*)p;        p += 256 * KP * 2;
    float* bb1 = (float*)p;        p += 256 * 4;
    short* Wt2 = (short*)p;        p += 256 * KP * 2;
    float* bb2 = (float*)p;

    hipMemsetAsync(cnt, 0, (size_t)N_TOT * 4, stream);
    hipMemsetAsync(xcA + (size_t)N_TOT * 128, 0, 512, stream);   // zero row A
    hipMemsetAsync(xcB + (size_t)N_TOT * 128, 0, 512, stream);   // zero row B
    fill_adj_kernel<<<(E_TOT + 255) / 256, 256, 0, stream>>>(edges, cnt, adj);
    pad_adj_kernel<<<(N_TOT + 255) / 256, 256, 0, stream>>>(cnt, adj);
    conv_w_kernel<<<256, 256, 0, stream>>>(w0_1, b0_1, w1_1, b1_1, Wt1, bb1);
    conv_w_kernel<<<256, 256, 0, stream>>>(w0_2, b0_2, w1_2, b1_2, Wt2, bb2);

    // layer 0 (mesh->XCD swizzled writes)
    mm3_kernel<<<8 * 4 * MM3_BPM, 256, 0, stream>>>(normals, w0_0, b0_0, w1_0, b1_0, xcA);
    // layer 1: gather(A) -> GEMM -> B
    fused_kernel<<<8 * 4 * FUS_BPM, 1024, 0, stream>>>(xcA, normals, cnt, adj, Wt1, bb1, xcB);
    // layer 2: gather(B) -> GEMM -> A
    fused_kernel<<<8 * 4 * FUS_BPM, 1024, 0, stream>>>(xcB, normals, cnt, adj, Wt2, bb2, xcA);
    // final: gather(A) -> h + verts (writes overlay dead xcB region)
    final_fused_kernel<<<8 * 4 * FIN_BPM, 256, 0, stream>>>(xcA, cnt, adj, normals, verts,
                                                            anchor_v, part_id, w_off, b_off,
                                                            hout, out_verts);
}